// Round 15
// baseline (1587.039 us; speedup 1.0000x reference)
//
#include <hip/hip_runtime.h>

typedef unsigned short u16;
typedef unsigned int u32;
typedef __attribute__((ext_vector_type(8))) short short8;
typedef __attribute__((ext_vector_type(4))) float f32x4;

__device__ __forceinline__ u16 f2b(float f) {
  union { float f; u32 u; } v; v.f = f;
  u32 r = v.u + 0x7fffu + ((v.u >> 16) & 1u);
  return (u16)(r >> 16);
}

__device__ __forceinline__ float b2f(u16 u) {
  union { u32 u; float f; } v; v.u = (u32)u << 16;
  return v.f;
}

__device__ __forceinline__ float gelu_tanh(float x) {
  float t = tanhf(0.7978845608028654f * (x + 0.044715f * x * x * x));
  return 0.5f * x * (1.0f + t);
}

__device__ __forceinline__ void async16(const void* g, void* l) {
  __builtin_amdgcn_global_load_lds(
      (const __attribute__((address_space(1))) u32*)g,
      (__attribute__((address_space(3))) u32*)l, 16, 0, 0);
}

// swizzled LDS vector read helper for flash kernel (row-major + row-XOR)
__device__ __forceinline__ short8 lds8(const u16* base, int row, int rowstride_b, int kb) {
  int addr = row * rowstride_b + kb;
  addr ^= (row & 7) << 4;
  return *(const short8*)((const char*)base + addr);
}

// -------------------------------------------------- merged prep kernel
// segments: [0,12288) qkv tcast, [12288,16384) proj, [16384,32768) fc,
// [32768,49152) fc2, [49152,81152) wte cast, [81152,85248) embed+LN1(l=0)
__global__ __launch_bounds__(256) void prep_k(
    const float* __restrict__ qkv_w, const float* __restrict__ proj_w,
    const float* __restrict__ fc_w, const float* __restrict__ fc2_w,
    const float* __restrict__ wte, const float* __restrict__ wpe,
    const int* __restrict__ ids,
    const float* __restrict__ ln1_g, const float* __restrict__ ln1_b,
    u16* __restrict__ wqkvT, u16* __restrict__ wprojT,
    u16* __restrict__ wfcT, u16* __restrict__ wfc2T,
    u16* __restrict__ wteB, u16* __restrict__ xbuf, u16* __restrict__ hbf) {
  const int blk = blockIdx.x;
  const int tid = threadIdx.x;
  if (blk >= 81152) {  // fused embed + LN1(layer0)
    const int row = blk - 81152;
    const int t = row & 2047;
    const long id = ids[row];
    float4 a = ((const float4*)(wte + id * 1024))[tid];
    float4 p = ((const float4*)(wpe + (long)t * 1024))[tid];
    ushort4 o;
    o.x = f2b(a.x + p.x); o.y = f2b(a.y + p.y);
    o.z = f2b(a.z + p.z); o.w = f2b(a.w + p.w);
    ((ushort4*)(xbuf + (long)row * 1024))[tid] = o;
    const float v0 = b2f(o.x), v1 = b2f(o.y), v2 = b2f(o.z), v3 = b2f(o.w);
    float s = v0 + v1 + v2 + v3;
    float q = v0 * v0 + v1 * v1 + v2 * v2 + v3 * v3;
#pragma unroll
    for (int of = 32; of; of >>= 1) { s += __shfl_down(s, of); q += __shfl_down(q, of); }
    __shared__ float rs_[4], rq_[4];
    if ((tid & 63) == 0) { rs_[tid >> 6] = s; rq_[tid >> 6] = q; }
    __syncthreads();
    s = rs_[0] + rs_[1] + rs_[2] + rs_[3];
    q = rq_[0] + rq_[1] + rq_[2] + rq_[3];
    const float mean = s * (1.0f / 1024.0f);
    const float var = q * (1.0f / 1024.0f) - mean * mean;
    const float rstd = rsqrtf(var + 1e-5f);
    const int c = tid * 4;
    ushort4 o4;
    o4.x = f2b((v0 - mean) * rstd * ln1_g[c + 0] + ln1_b[c + 0]);
    o4.y = f2b((v1 - mean) * rstd * ln1_g[c + 1] + ln1_b[c + 1]);
    o4.z = f2b((v2 - mean) * rstd * ln1_g[c + 2] + ln1_b[c + 2]);
    o4.w = f2b((v3 - mean) * rstd * ln1_g[c + 3] + ln1_b[c + 3]);
    ((ushort4*)(hbf + (long)row * 1024))[tid] = o4;
    return;
  }
  if (blk >= 49152) {  // wte f32 -> bf16 flat cast
    const long i = (long)(blk - 49152) * 256 + tid;
    float4 v = ((const float4*)wte)[i];
    ushort4 o;
    o.x = f2b(v.x); o.y = f2b(v.y); o.z = f2b(v.z); o.w = f2b(v.w);
    ((ushort4*)wteB)[i] = o;
    return;
  }
  // transpose+cast segments
  const float* src; u16* dst; int R, C, gx, rem;
  if (blk < 12288)      { rem = blk;         src = qkv_w;  dst = wqkvT;  R = 1024; C = 3072; gx = 96;  }
  else if (blk < 16384) { rem = blk - 12288; src = proj_w; dst = wprojT; R = 1024; C = 1024; gx = 32;  }
  else if (blk < 32768) { rem = blk - 16384; src = fc_w;   dst = wfcT;   R = 1024; C = 4096; gx = 128; }
  else                  { rem = blk - 32768; src = fc2_w;  dst = wfc2T;  R = 4096; C = 1024; gx = 32;  }
  const int per = gx * (R >> 5);
  const int z = rem / per, r2 = rem % per;
  const int byy = r2 / gx, bxx = r2 % gx;
  src += (long)z * R * C;
  dst += (long)z * R * C;
  __shared__ float tl[32][33];
  const int c0 = bxx << 5, r0 = byy << 5;
  const int tx = tid & 31, ty = tid >> 5;
#pragma unroll
  for (int i = 0; i < 4; ++i)
    tl[ty + i * 8][tx] = src[(long)(r0 + ty + i * 8) * C + c0 + tx];
  __syncthreads();
#pragma unroll
  for (int i = 0; i < 4; ++i)
    dst[(long)(c0 + ty + i * 8) * R + r0 + tx] = f2b(tl[tx][ty + i * 8]);
}

// LN over bf16 residual stream -> bf16 out
__global__ __launch_bounds__(256) void ln_bf16_k(const u16* __restrict__ x,
                                                 const float* __restrict__ g,
                                                 const float* __restrict__ b,
                                                 u16* __restrict__ out) {
  const int row = blockIdx.x;
  const int tid = threadIdx.x;
  const ushort4 vu = ((const ushort4*)(x + (long)row * 1024))[tid];
  const float v0 = b2f(vu.x), v1 = b2f(vu.y), v2 = b2f(vu.z), v3 = b2f(vu.w);
  float s = v0 + v1 + v2 + v3;
  float q = v0 * v0 + v1 * v1 + v2 * v2 + v3 * v3;
#pragma unroll
  for (int o = 32; o; o >>= 1) { s += __shfl_down(s, o); q += __shfl_down(q, o); }
  __shared__ float rs_[4], rq_[4];
  if ((tid & 63) == 0) { rs_[tid >> 6] = s; rq_[tid >> 6] = q; }
  __syncthreads();
  s = rs_[0] + rs_[1] + rs_[2] + rs_[3];
  q = rq_[0] + rq_[1] + rq_[2] + rq_[3];
  const float mean = s * (1.0f / 1024.0f);
  const float var = q * (1.0f / 1024.0f) - mean * mean;
  const float rstd = rsqrtf(var + 1e-5f);
  const int c = tid * 4;
  ushort4 o4;
  o4.x = f2b((v0 - mean) * rstd * g[c + 0] + b[c + 0]);
  o4.y = f2b((v1 - mean) * rstd * g[c + 1] + b[c + 1]);
  o4.z = f2b((v2 - mean) * rstd * g[c + 2] + b[c + 2]);
  o4.w = f2b((v3 - mean) * rstd * g[c + 3] + b[c + 3]);
  ((ushort4*)(out + (long)row * 1024))[tid] = o4;
}

// ------------------------------------------------ fused flash attention
// grid (32 bh, 16 q-tiles): bh = blockIdx.x so all q-blocks of one head land
// on XCD bh%8 (default round-robin) -> that head's K/V stays in one L2.
__global__ __launch_bounds__(256) void flash_k(const u16* __restrict__ qkv,
                                               const u16* __restrict__ vT,
                                               u16* __restrict__ obf) {
  __shared__ u16 Qs[128 * 64];
  __shared__ u16 Ks[128 * 64];
  __shared__ u16 Vt[64 * 128];
  __shared__ u16 Ps[128 * 128];

  const int qorder[16] = {6, 13, 5, 12, 4, 11, 3, 10, 2, 9, 1, 8, 0, 7, 14, 15};
  const int qt = qorder[blockIdx.y];
  const int bh = blockIdx.x;
  const int b = bh >> 4, h = bh & 15;
  int qtl, fstart;
  if (qt < 7)       { qtl = qt;      fstart = 0; }
  else if (qt < 14) { qtl = qt - 7;  fstart = 896; }
  else              { qtl = qt - 14; fstart = 1792; }
  const int nkt = qtl + 1;

  const int tid = threadIdx.x;
  const int wave = tid >> 6, lane = tid & 63;
  const int lrw = lane & 15, lsel = lane >> 4;

  const long qrow0 = (long)(b * 2048 + fstart + qtl * 128);
  {
    const u16* g = qkv + qrow0 * 3072 + h * 64;
#pragma unroll
    for (int i = 0; i < 4; ++i) {
      const int e = (i * 256 + tid) * 8;
      const int row = e >> 6;
      const int colb = (e & 63) * 2;
      const int scolb = colb ^ ((row & 7) << 4);
      async16(g + (long)row * 3072 + (scolb >> 1), &Qs[(i * 256 + wave * 64) * 8]);
    }
  }

  float mrun[2][4], lrun[2][4];
  f32x4 oacc[2][4];
#pragma unroll
  for (int m = 0; m < 2; ++m)
#pragma unroll
    for (int r = 0; r < 4; ++r) { mrun[m][r] = -1e30f; lrun[m][r] = 0.f; }
#pragma unroll
  for (int m = 0; m < 2; ++m)
#pragma unroll
    for (int n = 0; n < 4; ++n) oacc[m][n] = f32x4{0.f, 0.f, 0.f, 0.f};

  for (int kt = 0; kt < nkt; ++kt) {
    __syncthreads();
    {
      const u16* g = qkv + ((long)(b * 2048 + fstart + kt * 128)) * 3072 + 1024 + h * 64;
#pragma unroll
      for (int i = 0; i < 4; ++i) {
        const int e = (i * 256 + tid) * 8;
        const int row = e >> 6;
        const int colb = (e & 63) * 2;
        const int scolb = colb ^ ((row & 7) << 4);
        async16(g + (long)row * 3072 + (scolb >> 1), &Ks[(i * 256 + wave * 64) * 8]);
      }
    }
    {
      const u16* g = vT + (long)bh * 64 * 2048 + fstart + kt * 128;
#pragma unroll
      for (int i = 0; i < 4; ++i) {
        const int e = (i * 256 + tid) * 8;
        const int row = e >> 7;
        const int colb = (e & 127) * 2;
        const int scolb = colb ^ ((row & 7) << 4);
        async16(g + (long)row * 2048 + (scolb >> 1), &Vt[(i * 256 + wave * 64) * 8]);
      }
    }
    __syncthreads();

    f32x4 sa[2][8];
#pragma unroll
    for (int m = 0; m < 2; ++m)
#pragma unroll
      for (int n = 0; n < 8; ++n) sa[m][n] = f32x4{0.f, 0.f, 0.f, 0.f};
    __builtin_amdgcn_s_setprio(1);
#pragma unroll
    for (int ks = 0; ks < 2; ++ks) {
      const int kb = (ks * 32 + lsel * 8) * 2;
      short8 aq[2];
#pragma unroll
      for (int m = 0; m < 2; ++m) aq[m] = lds8(Qs, wave * 32 + m * 16 + lrw, 128, kb);
#pragma unroll
      for (int n = 0; n < 8; ++n) {
        const short8 bk = lds8(Ks, n * 16 + lrw, 128, kb);
#pragma unroll
        for (int m = 0; m < 2; ++m)
          sa[m][n] = __builtin_amdgcn_mfma_f32_16x16x32_bf16(aq[m], bk, sa[m][n], 0, 0, 0);
      }
    }
    __builtin_amdgcn_s_setprio(0);

    const bool diag = (kt == qtl);
#pragma unroll
    for (int m = 0; m < 2; ++m) {
      float tm[4] = {-1e30f, -1e30f, -1e30f, -1e30f};
#pragma unroll
      for (int n = 0; n < 8; ++n)
#pragma unroll
        for (int r = 0; r < 4; ++r) {
          float s = sa[m][n][r] * 0.125f;
          if (diag) {
            const int row_l = wave * 32 + m * 16 + lsel * 4 + r;
            const int col_l = n * 16 + lrw;
            if (col_l > row_l) s = -1e30f;
          }
          sa[m][n][r] = s;
          tm[r] = fmaxf(tm[r], s);
        }
#pragma unroll
      for (int r = 0; r < 4; ++r) {
#pragma unroll
        for (int o = 1; o < 16; o <<= 1) tm[r] = fmaxf(tm[r], __shfl_xor(tm[r], o));
        const float mnew = fmaxf(mrun[m][r], tm[r]);
        const float sc_old = __expf(mrun[m][r] - mnew);
        mrun[m][r] = mnew;
        float rs = 0.f;
#pragma unroll
        for (int n = 0; n < 8; ++n) {
          const float p = __expf(sa[m][n][r] - mnew);
          sa[m][n][r] = p;
          rs += p;
        }
#pragma unroll
        for (int o = 1; o < 16; o <<= 1) rs += __shfl_xor(rs, o);
        lrun[m][r] = lrun[m][r] * sc_old + rs;
#pragma unroll
        for (int n2 = 0; n2 < 4; ++n2) oacc[m][n2][r] *= sc_old;
      }
    }

#pragma unroll
    for (int m = 0; m < 2; ++m)
#pragma unroll
      for (int n = 0; n < 8; ++n)
#pragma unroll
        for (int r = 0; r < 4; ++r) {
          const int row = wave * 32 + m * 16 + lsel * 4 + r;
          int addr = row * 256 + n * 32 + lrw * 2;
          addr ^= (row & 7) << 4;
          *(u16*)((char*)Ps + addr) = f2b(sa[m][n][r]);
        }
    asm volatile("s_waitcnt lgkmcnt(0)" ::: "memory");

    __builtin_amdgcn_s_setprio(1);
#pragma unroll
    for (int ks2 = 0; ks2 < 4; ++ks2) {
      const int kb = (ks2 * 32 + lsel * 8) * 2;
      short8 pa[2];
#pragma unroll
      for (int m = 0; m < 2; ++m) pa[m] = lds8(Ps, wave * 32 + m * 16 + lrw, 256, kb);
#pragma unroll
      for (int n2 = 0; n2 < 4; ++n2) {
        const short8 bv = lds8(Vt, n2 * 16 + lrw, 256, kb);
#pragma unroll
        for (int m = 0; m < 2; ++m)
          oacc[m][n2] = __builtin_amdgcn_mfma_f32_16x16x32_bf16(pa[m], bv, oacc[m][n2], 0, 0, 0);
      }
    }
    __builtin_amdgcn_s_setprio(0);
  }

  u16* dst = obf + qrow0 * 1024 + h * 64;
#pragma unroll
  for (int m = 0; m < 2; ++m)
#pragma unroll
    for (int r = 0; r < 4; ++r) {
      const float inv = 1.0f / lrun[m][r];
      const int row_l = wave * 32 + m * 16 + lsel * 4 + r;
#pragma unroll
      for (int n2 = 0; n2 < 4; ++n2)
        dst[(long)row_l * 1024 + n2 * 16 + lrw] = f2b(oacc[m][n2][r] * inv);
    }
}

// ------------------------------------------- 256x256 8-phase bf16 GEMM
// SW=true (f32 out): swapped MFMA -> full-line f32x4 stores (head: 343us,
//   WRITE exactly 512MB). SW=false: scalar epilogue (best for bf16 out).
// VT=true (qkv only): blocks with col0>=2048 write V directly transposed.
#define BAR8 __builtin_amdgcn_s_barrier()
#define LGK0                                         \
  asm volatile("s_waitcnt lgkmcnt(0)" ::: "memory"); \
  __builtin_amdgcn_sched_barrier(0)

#define QUAD(mq, nq)                                                       \
  {                                                                        \
    __builtin_amdgcn_s_setprio(1);                                         \
    _Pragma("unroll") for (int mm = 0; mm < 4; ++mm) {                     \
      _Pragma("unroll") for (int nn = 0; nn < 2; ++nn) {                   \
        _Pragma("unroll") for (int ks = 0; ks < 2; ++ks) {                 \
          if constexpr (SW)                                                \
            acc[(mq) * 4 + mm][(nq) * 2 + nn] =                            \
                __builtin_amdgcn_mfma_f32_16x16x32_bf16(                   \
                    bq[(nq) * 2 + nn][ks], af[mm][ks],                     \
                    acc[(mq) * 4 + mm][(nq) * 2 + nn], 0, 0, 0);           \
          else                                                             \
            acc[(mq) * 4 + mm][(nq) * 2 + nn] =                            \
                __builtin_amdgcn_mfma_f32_16x16x32_bf16(                   \
                    af[mm][ks], bq[(nq) * 2 + nn][ks],                     \
                    acc[(mq) * 4 + mm][(nq) * 2 + nn], 0, 0, 0);           \
        }                                                                  \
      }                                                                    \
    }                                                                      \
    __builtin_amdgcn_s_setprio(0);                                         \
  }

#define LDA8(buf, fb)                                                       \
  {                                                                         \
    _Pragma("unroll") for (int ff = 0; ff < 4; ++ff) {                      \
      _Pragma("unroll") for (int ks = 0; ks < 2; ++ks) {                    \
        af[ff][ks] = ldfrag(&As[buf][wm][0], ((fb) + ff) * 16 + lrow, ks);  \
      }                                                                     \
    }                                                                       \
  }

#define LDB8(buf)                                                           \
  {                                                                         \
    _Pragma("unroll") for (int nn = 0; nn < 4; ++nn) {                      \
      _Pragma("unroll") for (int ks = 0; ks < 2; ++ks) {                    \
        bq[nn][ks] = ldfrag(&Bs[buf][wn >> 1][0], bro + nn * 16, ks);       \
      }                                                                     \
    }                                                                       \
  }

template <int EPI, bool SW, bool VT>
__global__ __launch_bounds__(512, 1)
void gemm8(const u16* __restrict__ A, const u16* __restrict__ Bt,
           void* __restrict__ Cv, const float* __restrict__ bias,
           int K, long lda, long ldb, long ldc, u16* __restrict__ vtb) {
  __shared__ u16 As[2][2][8192];
  __shared__ u16 Bs[2][2][8192];

  const int bx = blockIdx.x, by = blockIdx.y;

  const int tid = threadIdx.x;
  const int wave = tid >> 6, lane = tid & 63;
  const int wm = wave >> 2, wn = wave & 3;
  const int lrow = lane & 15, lsel = lane >> 4;
  const int row0 = by * 256, col0 = bx * 256;
  const int bro = (wn & 1) * 64 + lrow;
  const int NIT = K >> 7;

  auto stage = [&](const u16* g, long ld, int rbase, int k0, u16* lhalf) {
#pragma unroll
    for (int i = 0; i < 2; ++i) {
      const int j = i * 512 + tid;
      const int rl = (j >> 2) & 15;
      const int cq = (j & 3) ^ (((rl >> 3) & 1) << 1);
      const int grow = ((j >> 7) << 4) + rl;
      const int gcol = (((j >> 6) & 1) << 5) + cq * 8;
      async16(g + (long)(rbase + grow) * ld + k0 + gcol,
              lhalf + (i * 512 + wave * 64) * 8);
    }
  };
  auto ldfrag = [&](const u16* half, int rr, int ks) -> short8 {
    int byteoff = ((rr >> 4) << 11) + (ks << 10) + ((rr & 15) << 6) + (lsel << 4);
    byteoff ^= ((rr >> 3) & 1) << 5;
    return *(const short8*)((const char*)half + byteoff);
  };

  f32x4 acc[8][4];
#pragma unroll
  for (int m = 0; m < 8; ++m)
#pragma unroll
    for (int n = 0; n < 4; ++n) acc[m][n] = f32x4{0.f, 0.f, 0.f, 0.f};

  // prologue: kt0 fully + kt1 {A-h0, B-h0, B-h1}  (7 half-tiles, 14 loads)
  stage(A, lda, row0 + 0,   0,  &As[0][0][0]);
  stage(A, lda, row0 + 128, 0,  &As[0][1][0]);
  stage(Bt, ldb, col0 + 0,   0, &Bs[0][0][0]);
  stage(Bt, ldb, col0 + 128, 0, &Bs[0][1][0]);
  stage(A, lda, row0 + 0,   64, &As[1][0][0]);
  stage(Bt, ldb, col0 + 0,  64, &Bs[1][0][0]);
  stage(Bt, ldb, col0 + 128, 64, &Bs[1][1][0]);
  asm volatile("s_waitcnt vmcnt(6)" ::: "memory");
  BAR8;

  for (int i2 = 0; i2 < NIT; ++i2) {
    const int ke = i2 << 7;
    const bool nl = (i2 + 1 < NIT);
    short8 af[4][2], bq[4][2];
    // p1
    LDA8(0, 0);
    LDB8(0);
    stage(A, lda, row0 + 128, ke + 64, &As[1][1][0]);
    BAR8; LGK0;
    QUAD(0, 0);
    BAR8;
    // p2
    if (nl) stage(Bt, ldb, col0 + 0, ke + 128, &Bs[0][0][0]);
    BAR8;
    QUAD(0, 1);
    BAR8;
    // p3
    LDA8(0, 4);
    if (nl) stage(Bt, ldb, col0 + 128, ke + 128, &Bs[0][1][0]);
    BAR8; LGK0;
    QUAD(1, 0);
    BAR8;
    // p4
    if (nl) stage(A, lda, row0 + 0, ke + 128, &As[0][0][0]);
    BAR8;
    QUAD(1, 1);
    if (nl) { asm volatile("s_waitcnt vmcnt(6)" ::: "memory"); }
    else    { asm volatile("s_waitcnt vmcnt(0)" ::: "memory"); }
    BAR8;
    // p5
    LDA8(1, 0);
    LDB8(1);
    if (nl) stage(A, lda, row0 + 128, ke + 128, &As[0][1][0]);
    BAR8; LGK0;
    QUAD(0, 0);
    BAR8;
    // p6
    if (nl) stage(Bt, ldb, col0 + 0, ke + 192, &Bs[1][0][0]);
    BAR8;
    QUAD(0, 1);
    BAR8;
    // p7
    LDA8(1, 4);
    if (nl) stage(Bt, ldb, col0 + 128, ke + 192, &Bs[1][1][0]);
    BAR8; LGK0;
    QUAD(1, 0);
    BAR8;
    // p8
    if (nl) stage(A, lda, row0 + 0, ke + 192, &As[1][0][0]);
    BAR8;
    QUAD(1, 1);
    if (nl) { asm volatile("s_waitcnt vmcnt(6)" ::: "memory"); }
    BAR8;
  }

  if constexpr (SW) {
    const int rowb = row0 + wm * 128 + lrow;
    const int colb = col0 + wn * 64 + lsel * 4;
#pragma unroll
    for (int mm = 0; mm < 8; ++mm) {
#pragma unroll
      for (int nn = 0; nn < 4; ++nn) {
        const long idx = (long)(rowb + mm * 16) * ldc + colb + nn * 16;
        *(f32x4*)((float*)Cv + idx) = acc[mm][nn];
      }
    }
  } else {
    u16* C16 = (u16*)Cv;
    float* C32 = (float*)Cv;
    const int rowb = row0 + wm * 128, colb = col0 + wn * 64;
    bool vpath = false;
    if constexpr (VT) vpath = (col0 >= 2048);
    if (vpath) {
#pragma unroll
      for (int mm = 0; mm < 8; ++mm) {
#pragma unroll
        for (int nn = 0; nn < 4; ++nn) {
          const int col = colb + nn * 16 + lrow;
          const float bv = bias[col];
          const int dv = col - 2048;
          const int row = rowb + mm * 16 + lsel * 4;
          ushort4 o4;
          o4.x = f2b(acc[mm][nn][0] + bv);
          o4.y = f2b(acc[mm][nn][1] + bv);
          o4.z = f2b(acc[mm][nn][2] + bv);
          o4.w = f2b(acc[mm][nn][3] + bv);
          const long vaddr = ((long)((row >> 11) * 1024 + dv)) * 2048 + (row & 2047);
          *(ushort4*)&vtb[vaddr] = o4;
        }
      }
    } else {
#pragma unroll
      for (int mm = 0; mm < 8; ++mm) {
#pragma unroll
        for (int nn = 0; nn < 4; ++nn) {
          const int col = colb + nn * 16 + lrow;
          float bv = 0.f;
          if constexpr (EPI == 2 || EPI == 3) bv = bias[col];
#pragma unroll
          for (int r = 0; r < 4; ++r) {
            const int row = rowb + mm * 16 + lsel * 4 + r;
            const long idx = (long)row * ldc + col;
            const float v = acc[mm][nn][r] + bv;
            if constexpr (EPI == 0) C32[idx] = v;
            else if constexpr (EPI == 2) C16[idx] = f2b(v);
            else C16[idx] = f2b(gelu_tanh(v));
          }
        }
      }
    }
  }
}

// --------------------------------------------------------------- 128xBN GEMM
// proj/fc2: EPI=1 -> bf16 residual read + bf16 write (x = resid + Wx + b)
template <int BM, int BN, int WGM, int WGN, int EPI>
__global__ __launch_bounds__(WGM * WGN * 64)
void gemm_bt(const u16* __restrict__ A, const u16* __restrict__ Bt,
             void* Cv, const float* __restrict__ bias, const u16* resid,
             int M, int N, int K, int lda, int ldb, int ldc) {
  constexpr int BK = 64;
  constexpr int NT = WGM * WGN * 64;
  constexpr int WM = BM / WGM, WN = BN / WGN;
  constexpr int MF = WM / 16, NF = WN / 16;
  constexpr int AIT = (BM * BK) / (NT * 8);
  constexpr int BIT = (BN * BK) / (NT * 8);
  static_assert(AIT >= 1 && BIT >= 1, "staging shape");

  __shared__ u16 As[BM * BK];
  __shared__ u16 Bs[BN * BK];

  const int tid = threadIdx.x;
  const int wave = tid >> 6, lane = tid & 63;
  const int wr = wave / WGN, wc = wave % WGN;
  const int lrow = lane & 15, lsel = lane >> 4;
  const int row0 = blockIdx.y * BM;
  const int col0 = blockIdx.x * BN;

  f32x4 acc[MF][NF];
#pragma unroll
  for (int m = 0; m < MF; ++m)
#pragma unroll
    for (int n = 0; n < NF; ++n) acc[m][n] = f32x4{0.f, 0.f, 0.f, 0.f};

  for (int k0 = 0; k0 < K; k0 += BK) {
#pragma unroll
    for (int i = 0; i < AIT; ++i) {
      const int e = (i * NT + tid) * 8;
      const int rr = e >> 6, cc = e & 63;
      async16(A + (long)(row0 + rr) * lda + k0 + cc, &As[(i * NT + wave * 64) * 8]);
    }
#pragma unroll
    for (int i = 0; i < BIT; ++i) {
      const int e = (i * NT + tid) * 8;
      const int rr = e >> 6, cc = e & 63;
      async16(Bt + (long)(col0 + rr) * ldb + k0 + cc, &Bs[(i * NT + wave * 64) * 8]);
    }
    __syncthreads();
#pragma unroll
    for (int ks = 0; ks < 2; ++ks) {
      short8 af[MF], bfr[NF];
#pragma unroll
      for (int m = 0; m < MF; ++m)
        af[m] = *(const short8*)&As[(wr * WM + m * 16 + lrow) * BK + ks * 32 + lsel * 8];
#pragma unroll
      for (int n = 0; n < NF; ++n)
        bfr[n] = *(const short8*)&Bs[(wc * WN + n * 16 + lrow) * BK + ks * 32 + lsel * 8];
#pragma unroll
      for (int m = 0; m < MF; ++m)
#pragma unroll
        for (int n = 0; n < NF; ++n)
          acc[m][n] = __builtin_amdgcn_mfma_f32_16x16x32_bf16(af[m], bfr[n], acc[m][n], 0, 0, 0);
    }
    __syncthreads();
  }

#pragma unroll
  for (int m = 0; m < MF; ++m) {
#pragma unroll
    for (int n = 0; n < NF; ++n) {
      const int row = row0 + wr * WM + m * 16 + lsel * 4;
      const int col = col0 + wc * WN + n * 16 + lrow;
      float bv = 0.f;
      if constexpr (EPI == 1 || EPI == 2 || EPI == 3) bv = bias[col];
#pragma unroll
      for (int r = 0; r < 4; ++r) {
        const long idx = (long)(row + r) * ldc + col;
        const float v = acc[m][n][r] + bv;
        if constexpr (EPI == 0) ((float*)Cv)[idx] = v;
        else if constexpr (EPI == 1) ((u16*)Cv)[idx] = f2b(b2f(resid[idx]) + v);
        else if constexpr (EPI == 2) ((u16*)Cv)[idx] = f2b(v);
        else if constexpr (EPI == 3) ((u16*)Cv)[idx] = f2b(gelu_tanh(v));
        else ((u16*)Cv)[idx] = f2b(v);
      }
    }
  }
}

// ------------------------------------------------------------------ driver

extern "C" void kernel_launch(void* const* d_in, const int* in_sizes, int n_in,
                              void* d_out, int out_size, void* d_ws, size_t ws_size,
                              hipStream_t stream) {
  (void)in_sizes; (void)n_in; (void)out_size; (void)ws_size;
  const int*   ids    = (const int*)d_in[0];
  const float* wte    = (const float*)d_in[2];
  const float* wpe    = (const float*)d_in[3];
  const float* ln1_g  = (const float*)d_in[4];
  const float* ln1_b  = (const float*)d_in[5];
  const float* qkv_w  = (const float*)d_in[6];
  const float* qkv_b  = (const float*)d_in[7];
  const float* proj_w = (const float*)d_in[8];
  const float* proj_b = (const float*)d_in[9];
  const float* ln2_g  = (const float*)d_in[10];
  const float* ln2_b  = (const float*)d_in[11];
  const float* fc_w   = (const float*)d_in[12];
  const float* fc_b   = (const float*)d_in[13];
  const float* fc2_w  = (const float*)d_in[14];
  const float* fc2_b  = (const float*)d_in[15];
  const float* lnf_g  = (const float*)d_in[16];
  const float* lnf_b  = (const float*)d_in[17];
  float* out = (float*)d_out;

  char* base = (char*)d_ws;
  size_t off = 0;
  auto alloc = [&](size_t bytes) -> void* {
    void* r = base + off;
    off += (bytes + 255) & ~(size_t)255;
    return r;
  };
  u16*   wqkvT  = (u16*)alloc((size_t)4 * 3072 * 1024 * 2);
  u16*   wprojT = (u16*)alloc((size_t)4 * 1024 * 1024 * 2);
  u16*   wfcT   = (u16*)alloc((size_t)4 * 4096 * 1024 * 2);
  u16*   wfc2T  = (u16*)alloc((size_t)4 * 1024 * 4096 * 2);
  u16*   wteB   = (u16*)alloc((size_t)32000 * 1024 * 2);
  u16*   xbuf   = (u16*)alloc((size_t)4096 * 1024 * 2);
  u16*   hbf    = (u16*)alloc((size_t)4096 * 1024 * 2);
  u16*   qkvbf  = (u16*)alloc((size_t)4096 * 3072 * 2);
  u16*   vTb    = (u16*)alloc((size_t)32 * 64 * 2048 * 2);
  u16*   obf    = (u16*)alloc((size_t)4096 * 1024 * 2);
  u16*   fcbf   = (u16*)alloc((size_t)4096 * 4096 * 2);

  // ---- single merged prep launch: all weight transforms + embed+LN1(l=0)
  prep_k<<<85248, 256, 0, stream>>>(qkv_w, proj_w, fc_w, fc2_w, wte, wpe, ids,
                                    ln1_g, ln1_b,
                                    wqkvT, wprojT, wfcT, wfc2T, wteB, xbuf, hbf);

  for (int l = 0; l < 4; ++l) {
    if (l > 0)
      ln_bf16_k<<<4096, 256, 0, stream>>>(xbuf, ln1_g + l * 1024, ln1_b + l * 1024, hbf);
    // qkv = LN1 @ Wqkv + b; Q,K -> qkvbf; V -> vTb (transposed in-epilogue)
    gemm8<2, false, true><<<dim3(12, 16), 512, 0, stream>>>(
        hbf, wqkvT + (size_t)l * 3072 * 1024, qkvbf, qkv_b + l * 3072,
        1024, 1024, 1024, 3072, vTb);
    // flash attention: bh-major grid -> per-head K/V stays in one XCD's L2
    flash_k<<<dim3(32, 16), 256, 0, stream>>>(qkvbf, vTb, obf);
    // x = x + O @ Wproj + b   (bf16 residual stream)
    gemm_bt<128, 64, 2, 2, 1><<<dim3(16, 32, 1), 256, 0, stream>>>(
        obf, wprojT + (size_t)l * 1024 * 1024, xbuf, proj_b + l * 1024, xbuf,
        4096, 1024, 1024, 1024, 1024, 1024);
    ln_bf16_k<<<4096, 256, 0, stream>>>(xbuf, ln2_g + l * 1024, ln2_b + l * 1024, hbf);
    // fcact = gelu(LN2 @ Wfc + b) -> bf16   (8-phase 256^2, scalar epi)
    gemm8<3, false, false><<<dim3(16, 16), 512, 0, stream>>>(
        hbf, wfcT + (size_t)l * 4096 * 1024, fcbf, fc_b + l * 4096,
        1024, 1024, 1024, 4096, nullptr);
    // x = x + fcact @ Wfc2 + b   (bf16 residual stream)
    gemm_bt<128, 64, 2, 2, 1><<<dim3(16, 32, 1), 256, 0, stream>>>(
        fcbf, wfc2T + (size_t)l * 1024 * 4096, xbuf, fc2_b + l * 1024, xbuf,
        4096, 1024, 4096, 4096, 4096, 1024);
  }
  ln_bf16_k<<<4096, 256, 0, stream>>>(xbuf, lnf_g, lnf_b, hbf);
  // logits = lnf @ wte^T  (8-phase 256^2, swapped + full-line f32x4 stores)
  gemm8<0, true, false><<<dim3(125, 16), 512, 0, stream>>>(
      hbf, wteB, out, nullptr, 1024, 1024, 1024, 32000, nullptr);
}

// Round 16
// 1515.632 us; speedup vs baseline: 1.0471x; 1.0471x over previous
//
#include <hip/hip_runtime.h>

typedef unsigned short u16;
typedef unsigned int u32;
typedef __attribute__((ext_vector_type(8))) short short8;
typedef __attribute__((ext_vector_type(4))) float f32x4;

__device__ __forceinline__ u16 f2b(float f) {
  union { float f; u32 u; } v; v.f = f;
  u32 r = v.u + 0x7fffu + ((v.u >> 16) & 1u);
  return (u16)(r >> 16);
}

__device__ __forceinline__ float b2f(u16 u) {
  union { u32 u; float f; } v; v.u = (u32)u << 16;
  return v.f;
}

__device__ __forceinline__ float gelu_tanh(float x) {
  float t = tanhf(0.7978845608028654f * (x + 0.044715f * x * x * x));
  return 0.5f * x * (1.0f + t);
}

__device__ __forceinline__ void async16(const void* g, void* l) {
  __builtin_amdgcn_global_load_lds(
      (const __attribute__((address_space(1))) u32*)g,
      (__attribute__((address_space(3))) u32*)l, 16, 0, 0);
}

// swizzled LDS vector read helper for flash kernel (row-major + row-XOR)
__device__ __forceinline__ short8 lds8(const u16* base, int row, int rowstride_b, int kb) {
  int addr = row * rowstride_b + kb;
  addr ^= (row & 7) << 4;
  return *(const short8*)((const char*)base + addr);
}

// ---------------------------------------------------------------- utilities

__global__ __launch_bounds__(256) void castbf_k(const float* __restrict__ src,
                                                u16* __restrict__ dst, long n4) {
  long i = (long)blockIdx.x * 256 + threadIdx.x;
  if (i >= n4) return;
  float4 v = ((const float4*)src)[i];
  ushort4 o;
  o.x = f2b(v.x); o.y = f2b(v.y); o.z = f2b(v.z); o.w = f2b(v.w);
  ((ushort4*)dst)[i] = o;
}

// transpose + cast: src f32 [R][C]  ->  dst bf16 [C][R]
__global__ __launch_bounds__(256) void tcast32_k(const float* __restrict__ src,
                                                 u16* __restrict__ dst,
                                                 int R, int C, long sB, long dB) {
  src += (long)blockIdx.z * sB;
  dst += (long)blockIdx.z * dB;
  __shared__ float tl[32][33];
  const int c0 = blockIdx.x << 5, r0 = blockIdx.y << 5;
  const int tx = threadIdx.x & 31, ty = threadIdx.x >> 5;
#pragma unroll
  for (int i = 0; i < 4; ++i)
    tl[ty + i * 8][tx] = src[(long)(r0 + ty + i * 8) * C + c0 + tx];
  __syncthreads();
#pragma unroll
  for (int i = 0; i < 4; ++i)
    dst[(long)(c0 + ty + i * 8) * R + r0 + tx] = f2b(tl[tx][ty + i * 8]);
}

// fused embed + LN1(layer0): x = wte[id]+wpe -> bf16 xbuf; LN(x) -> hbf.
// LN stats computed on the bf16-rounded values (bit-identical to 2-kernel path).
__global__ __launch_bounds__(256) void embed_ln_k(const int* __restrict__ ids,
                                                  const float* __restrict__ wte,
                                                  const float* __restrict__ wpe,
                                                  const float* __restrict__ g,
                                                  const float* __restrict__ b,
                                                  u16* __restrict__ x,
                                                  u16* __restrict__ out) {
  const int row = blockIdx.x;
  const int tid = threadIdx.x;
  const int t = row & 2047;
  const long id = ids[row];
  float4 a = ((const float4*)(wte + id * 1024))[tid];
  float4 p = ((const float4*)(wpe + (long)t * 1024))[tid];
  ushort4 o;
  o.x = f2b(a.x + p.x); o.y = f2b(a.y + p.y);
  o.z = f2b(a.z + p.z); o.w = f2b(a.w + p.w);
  ((ushort4*)(x + (long)row * 1024))[tid] = o;
  const float v0 = b2f(o.x), v1 = b2f(o.y), v2 = b2f(o.z), v3 = b2f(o.w);
  float s = v0 + v1 + v2 + v3;
  float q = v0 * v0 + v1 * v1 + v2 * v2 + v3 * v3;
#pragma unroll
  for (int of = 32; of; of >>= 1) { s += __shfl_down(s, of); q += __shfl_down(q, of); }
  __shared__ float rs_[4], rq_[4];
  if ((tid & 63) == 0) { rs_[tid >> 6] = s; rq_[tid >> 6] = q; }
  __syncthreads();
  s = rs_[0] + rs_[1] + rs_[2] + rs_[3];
  q = rq_[0] + rq_[1] + rq_[2] + rq_[3];
  const float mean = s * (1.0f / 1024.0f);
  const float var = q * (1.0f / 1024.0f) - mean * mean;
  const float rstd = rsqrtf(var + 1e-5f);
  const int c = tid * 4;
  ushort4 o4;
  o4.x = f2b((v0 - mean) * rstd * g[c + 0] + b[c + 0]);
  o4.y = f2b((v1 - mean) * rstd * g[c + 1] + b[c + 1]);
  o4.z = f2b((v2 - mean) * rstd * g[c + 2] + b[c + 2]);
  o4.w = f2b((v3 - mean) * rstd * g[c + 3] + b[c + 3]);
  ((ushort4*)(out + (long)row * 1024))[tid] = o4;
}

// LN over bf16 residual stream -> bf16 out
__global__ __launch_bounds__(256) void ln_bf16_k(const u16* __restrict__ x,
                                                 const float* __restrict__ g,
                                                 const float* __restrict__ b,
                                                 u16* __restrict__ out) {
  const int row = blockIdx.x;
  const int tid = threadIdx.x;
  const ushort4 vu = ((const ushort4*)(x + (long)row * 1024))[tid];
  const float v0 = b2f(vu.x), v1 = b2f(vu.y), v2 = b2f(vu.z), v3 = b2f(vu.w);
  float s = v0 + v1 + v2 + v3;
  float q = v0 * v0 + v1 * v1 + v2 * v2 + v3 * v3;
#pragma unroll
  for (int o = 32; o; o >>= 1) { s += __shfl_down(s, o); q += __shfl_down(q, o); }
  __shared__ float rs_[4], rq_[4];
  if ((tid & 63) == 0) { rs_[tid >> 6] = s; rq_[tid >> 6] = q; }
  __syncthreads();
  s = rs_[0] + rs_[1] + rs_[2] + rs_[3];
  q = rq_[0] + rq_[1] + rq_[2] + rq_[3];
  const float mean = s * (1.0f / 1024.0f);
  const float var = q * (1.0f / 1024.0f) - mean * mean;
  const float rstd = rsqrtf(var + 1e-5f);
  const int c = tid * 4;
  ushort4 o4;
  o4.x = f2b((v0 - mean) * rstd * g[c + 0] + b[c + 0]);
  o4.y = f2b((v1 - mean) * rstd * g[c + 1] + b[c + 1]);
  o4.z = f2b((v2 - mean) * rstd * g[c + 2] + b[c + 2]);
  o4.w = f2b((v3 - mean) * rstd * g[c + 3] + b[c + 3]);
  ((ushort4*)(out + (long)row * 1024))[tid] = o4;
}

// ------------------------------------------------ fused flash attention
// grid (32 bh, 16 q-tiles): bh = blockIdx.x so all q-blocks of one head land
// on XCD bh%8 (default round-robin) -> that head's K/V stays in one L2.
__global__ __launch_bounds__(256) void flash_k(const u16* __restrict__ qkv,
                                               const u16* __restrict__ vT,
                                               u16* __restrict__ obf) {
  __shared__ u16 Qs[128 * 64];
  __shared__ u16 Ks[128 * 64];
  __shared__ u16 Vt[64 * 128];
  __shared__ u16 Ps[128 * 128];

  const int qorder[16] = {6, 13, 5, 12, 4, 11, 3, 10, 2, 9, 1, 8, 0, 7, 14, 15};
  const int qt = qorder[blockIdx.y];
  const int bh = blockIdx.x;
  const int b = bh >> 4, h = bh & 15;
  int qtl, fstart;
  if (qt < 7)       { qtl = qt;      fstart = 0; }
  else if (qt < 14) { qtl = qt - 7;  fstart = 896; }
  else              { qtl = qt - 14; fstart = 1792; }
  const int nkt = qtl + 1;

  const int tid = threadIdx.x;
  const int wave = tid >> 6, lane = tid & 63;
  const int lrw = lane & 15, lsel = lane >> 4;

  const long qrow0 = (long)(b * 2048 + fstart + qtl * 128);
  {
    const u16* g = qkv + qrow0 * 3072 + h * 64;
#pragma unroll
    for (int i = 0; i < 4; ++i) {
      const int e = (i * 256 + tid) * 8;
      const int row = e >> 6;
      const int colb = (e & 63) * 2;
      const int scolb = colb ^ ((row & 7) << 4);
      async16(g + (long)row * 3072 + (scolb >> 1), &Qs[(i * 256 + wave * 64) * 8]);
    }
  }

  float mrun[2][4], lrun[2][4];
  f32x4 oacc[2][4];
#pragma unroll
  for (int m = 0; m < 2; ++m)
#pragma unroll
    for (int r = 0; r < 4; ++r) { mrun[m][r] = -1e30f; lrun[m][r] = 0.f; }
#pragma unroll
  for (int m = 0; m < 2; ++m)
#pragma unroll
    for (int n = 0; n < 4; ++n) oacc[m][n] = f32x4{0.f, 0.f, 0.f, 0.f};

  for (int kt = 0; kt < nkt; ++kt) {
    __syncthreads();
    {
      const u16* g = qkv + ((long)(b * 2048 + fstart + kt * 128)) * 3072 + 1024 + h * 64;
#pragma unroll
      for (int i = 0; i < 4; ++i) {
        const int e = (i * 256 + tid) * 8;
        const int row = e >> 6;
        const int colb = (e & 63) * 2;
        const int scolb = colb ^ ((row & 7) << 4);
        async16(g + (long)row * 3072 + (scolb >> 1), &Ks[(i * 256 + wave * 64) * 8]);
      }
    }
    {
      const u16* g = vT + (long)bh * 64 * 2048 + fstart + kt * 128;
#pragma unroll
      for (int i = 0; i < 4; ++i) {
        const int e = (i * 256 + tid) * 8;
        const int row = e >> 7;
        const int colb = (e & 127) * 2;
        const int scolb = colb ^ ((row & 7) << 4);
        async16(g + (long)row * 2048 + (scolb >> 1), &Vt[(i * 256 + wave * 64) * 8]);
      }
    }
    __syncthreads();

    f32x4 sa[2][8];
#pragma unroll
    for (int m = 0; m < 2; ++m)
#pragma unroll
      for (int n = 0; n < 8; ++n) sa[m][n] = f32x4{0.f, 0.f, 0.f, 0.f};
    __builtin_amdgcn_s_setprio(1);
#pragma unroll
    for (int ks = 0; ks < 2; ++ks) {
      const int kb = (ks * 32 + lsel * 8) * 2;
      short8 aq[2];
#pragma unroll
      for (int m = 0; m < 2; ++m) aq[m] = lds8(Qs, wave * 32 + m * 16 + lrw, 128, kb);
#pragma unroll
      for (int n = 0; n < 8; ++n) {
        const short8 bk = lds8(Ks, n * 16 + lrw, 128, kb);
#pragma unroll
        for (int m = 0; m < 2; ++m)
          sa[m][n] = __builtin_amdgcn_mfma_f32_16x16x32_bf16(aq[m], bk, sa[m][n], 0, 0, 0);
      }
    }
    __builtin_amdgcn_s_setprio(0);

    const bool diag = (kt == qtl);
#pragma unroll
    for (int m = 0; m < 2; ++m) {
      float tm[4] = {-1e30f, -1e30f, -1e30f, -1e30f};
#pragma unroll
      for (int n = 0; n < 8; ++n)
#pragma unroll
        for (int r = 0; r < 4; ++r) {
          float s = sa[m][n][r] * 0.125f;
          if (diag) {
            const int row_l = wave * 32 + m * 16 + lsel * 4 + r;
            const int col_l = n * 16 + lrw;
            if (col_l > row_l) s = -1e30f;
          }
          sa[m][n][r] = s;
          tm[r] = fmaxf(tm[r], s);
        }
#pragma unroll
      for (int r = 0; r < 4; ++r) {
#pragma unroll
        for (int o = 1; o < 16; o <<= 1) tm[r] = fmaxf(tm[r], __shfl_xor(tm[r], o));
        const float mnew = fmaxf(mrun[m][r], tm[r]);
        const float sc_old = __expf(mrun[m][r] - mnew);
        mrun[m][r] = mnew;
        float rs = 0.f;
#pragma unroll
        for (int n = 0; n < 8; ++n) {
          const float p = __expf(sa[m][n][r] - mnew);
          sa[m][n][r] = p;
          rs += p;
        }
#pragma unroll
        for (int o = 1; o < 16; o <<= 1) rs += __shfl_xor(rs, o);
        lrun[m][r] = lrun[m][r] * sc_old + rs;
#pragma unroll
        for (int n2 = 0; n2 < 4; ++n2) oacc[m][n2][r] *= sc_old;
      }
    }

#pragma unroll
    for (int m = 0; m < 2; ++m)
#pragma unroll
      for (int n = 0; n < 8; ++n)
#pragma unroll
        for (int r = 0; r < 4; ++r) {
          const int row = wave * 32 + m * 16 + lsel * 4 + r;
          int addr = row * 256 + n * 32 + lrw * 2;
          addr ^= (row & 7) << 4;
          *(u16*)((char*)Ps + addr) = f2b(sa[m][n][r]);
        }
    asm volatile("s_waitcnt lgkmcnt(0)" ::: "memory");

    __builtin_amdgcn_s_setprio(1);
#pragma unroll
    for (int ks2 = 0; ks2 < 4; ++ks2) {
      const int kb = (ks2 * 32 + lsel * 8) * 2;
      short8 pa[2];
#pragma unroll
      for (int m = 0; m < 2; ++m) pa[m] = lds8(Ps, wave * 32 + m * 16 + lrw, 256, kb);
#pragma unroll
      for (int n2 = 0; n2 < 4; ++n2) {
        const short8 bv = lds8(Vt, n2 * 16 + lrw, 256, kb);
#pragma unroll
        for (int m = 0; m < 2; ++m)
          oacc[m][n2] = __builtin_amdgcn_mfma_f32_16x16x32_bf16(pa[m], bv, oacc[m][n2], 0, 0, 0);
      }
    }
    __builtin_amdgcn_s_setprio(0);
  }

  u16* dst = obf + qrow0 * 1024 + h * 64;
#pragma unroll
  for (int m = 0; m < 2; ++m)
#pragma unroll
    for (int r = 0; r < 4; ++r) {
      const float inv = 1.0f / lrun[m][r];
      const int row_l = wave * 32 + m * 16 + lsel * 4 + r;
#pragma unroll
      for (int n2 = 0; n2 < 4; ++n2)
        dst[(long)row_l * 1024 + n2 * 16 + lrw] = f2b(oacc[m][n2][r] * inv);
    }
}

// ------------------------------------------- 256x256 8-phase bf16 GEMM
// SW=true (f32 out): swapped MFMA -> full-line f32x4 stores (head: 343us,
//   WRITE exactly 512MB). SW=false: scalar epilogue (best for bf16 out).
// VT=true (qkv only): blocks with col0>=2048 write V directly transposed.
#define BAR8 __builtin_amdgcn_s_barrier()
#define LGK0                                         \
  asm volatile("s_waitcnt lgkmcnt(0)" ::: "memory"); \
  __builtin_amdgcn_sched_barrier(0)

#define QUAD(mq, nq)                                                       \
  {                                                                        \
    __builtin_amdgcn_s_setprio(1);                                         \
    _Pragma("unroll") for (int mm = 0; mm < 4; ++mm) {                     \
      _Pragma("unroll") for (int nn = 0; nn < 2; ++nn) {                   \
        _Pragma("unroll") for (int ks = 0; ks < 2; ++ks) {                 \
          if constexpr (SW)                                                \
            acc[(mq) * 4 + mm][(nq) * 2 + nn] =                            \
                __builtin_amdgcn_mfma_f32_16x16x32_bf16(                   \
                    bq[(nq) * 2 + nn][ks], af[mm][ks],                     \
                    acc[(mq) * 4 + mm][(nq) * 2 + nn], 0, 0, 0);           \
          else                                                             \
            acc[(mq) * 4 + mm][(nq) * 2 + nn] =                            \
                __builtin_amdgcn_mfma_f32_16x16x32_bf16(                   \
                    af[mm][ks], bq[(nq) * 2 + nn][ks],                     \
                    acc[(mq) * 4 + mm][(nq) * 2 + nn], 0, 0, 0);           \
        }                                                                  \
      }                                                                    \
    }                                                                      \
    __builtin_amdgcn_s_setprio(0);                                         \
  }

#define LDA8(buf, fb)                                                       \
  {                                                                         \
    _Pragma("unroll") for (int ff = 0; ff < 4; ++ff) {                      \
      _Pragma("unroll") for (int ks = 0; ks < 2; ++ks) {                    \
        af[ff][ks] = ldfrag(&As[buf][wm][0], ((fb) + ff) * 16 + lrow, ks);  \
      }                                                                     \
    }                                                                       \
  }

#define LDB8(buf)                                                           \
  {                                                                         \
    _Pragma("unroll") for (int nn = 0; nn < 4; ++nn) {                      \
      _Pragma("unroll") for (int ks = 0; ks < 2; ++ks) {                    \
        bq[nn][ks] = ldfrag(&Bs[buf][wn >> 1][0], bro + nn * 16, ks);       \
      }                                                                     \
    }                                                                       \
  }

template <int EPI, bool SW, bool VT>
__global__ __launch_bounds__(512, 1)
void gemm8(const u16* __restrict__ A, const u16* __restrict__ Bt,
           void* __restrict__ Cv, const float* __restrict__ bias,
           int K, long lda, long ldb, long ldc, u16* __restrict__ vtb) {
  __shared__ u16 As[2][2][8192];
  __shared__ u16 Bs[2][2][8192];

  const int bx = blockIdx.x, by = blockIdx.y;

  const int tid = threadIdx.x;
  const int wave = tid >> 6, lane = tid & 63;
  const int wm = wave >> 2, wn = wave & 3;
  const int lrow = lane & 15, lsel = lane >> 4;
  const int row0 = by * 256, col0 = bx * 256;
  const int bro = (wn & 1) * 64 + lrow;
  const int NIT = K >> 7;

  auto stage = [&](const u16* g, long ld, int rbase, int k0, u16* lhalf) {
#pragma unroll
    for (int i = 0; i < 2; ++i) {
      const int j = i * 512 + tid;
      const int rl = (j >> 2) & 15;
      const int cq = (j & 3) ^ (((rl >> 3) & 1) << 1);
      const int grow = ((j >> 7) << 4) + rl;
      const int gcol = (((j >> 6) & 1) << 5) + cq * 8;
      async16(g + (long)(rbase + grow) * ld + k0 + gcol,
              lhalf + (i * 512 + wave * 64) * 8);
    }
  };
  auto ldfrag = [&](const u16* half, int rr, int ks) -> short8 {
    int byteoff = ((rr >> 4) << 11) + (ks << 10) + ((rr & 15) << 6) + (lsel << 4);
    byteoff ^= ((rr >> 3) & 1) << 5;
    return *(const short8*)((const char*)half + byteoff);
  };

  f32x4 acc[8][4];
#pragma unroll
  for (int m = 0; m < 8; ++m)
#pragma unroll
    for (int n = 0; n < 4; ++n) acc[m][n] = f32x4{0.f, 0.f, 0.f, 0.f};

  // prologue: kt0 fully + kt1 {A-h0, B-h0, B-h1}  (7 half-tiles, 14 loads)
  stage(A, lda, row0 + 0,   0,  &As[0][0][0]);
  stage(A, lda, row0 + 128, 0,  &As[0][1][0]);
  stage(Bt, ldb, col0 + 0,   0, &Bs[0][0][0]);
  stage(Bt, ldb, col0 + 128, 0, &Bs[0][1][0]);
  stage(A, lda, row0 + 0,   64, &As[1][0][0]);
  stage(Bt, ldb, col0 + 0,  64, &Bs[1][0][0]);
  stage(Bt, ldb, col0 + 128, 64, &Bs[1][1][0]);
  asm volatile("s_waitcnt vmcnt(6)" ::: "memory");
  BAR8;

  for (int i2 = 0; i2 < NIT; ++i2) {
    const int ke = i2 << 7;
    const bool nl = (i2 + 1 < NIT);
    short8 af[4][2], bq[4][2];
    // p1
    LDA8(0, 0);
    LDB8(0);
    stage(A, lda, row0 + 128, ke + 64, &As[1][1][0]);
    BAR8; LGK0;
    QUAD(0, 0);
    BAR8;
    // p2
    if (nl) stage(Bt, ldb, col0 + 0, ke + 128, &Bs[0][0][0]);
    BAR8;
    QUAD(0, 1);
    BAR8;
    // p3
    LDA8(0, 4);
    if (nl) stage(Bt, ldb, col0 + 128, ke + 128, &Bs[0][1][0]);
    BAR8; LGK0;
    QUAD(1, 0);
    BAR8;
    // p4
    if (nl) stage(A, lda, row0 + 0, ke + 128, &As[0][0][0]);
    BAR8;
    QUAD(1, 1);
    if (nl) { asm volatile("s_waitcnt vmcnt(6)" ::: "memory"); }
    else    { asm volatile("s_waitcnt vmcnt(0)" ::: "memory"); }
    BAR8;
    // p5
    LDA8(1, 0);
    LDB8(1);
    if (nl) stage(A, lda, row0 + 128, ke + 128, &As[0][1][0]);
    BAR8; LGK0;
    QUAD(0, 0);
    BAR8;
    // p6
    if (nl) stage(Bt, ldb, col0 + 0, ke + 192, &Bs[1][0][0]);
    BAR8;
    QUAD(0, 1);
    BAR8;
    // p7
    LDA8(1, 4);
    if (nl) stage(Bt, ldb, col0 + 128, ke + 192, &Bs[1][1][0]);
    BAR8; LGK0;
    QUAD(1, 0);
    BAR8;
    // p8
    if (nl) stage(A, lda, row0 + 0, ke + 192, &As[1][0][0]);
    BAR8;
    QUAD(1, 1);
    if (nl) { asm volatile("s_waitcnt vmcnt(6)" ::: "memory"); }
    BAR8;
  }

  if constexpr (SW) {
    const int rowb = row0 + wm * 128 + lrow;
    const int colb = col0 + wn * 64 + lsel * 4;
#pragma unroll
    for (int mm = 0; mm < 8; ++mm) {
#pragma unroll
      for (int nn = 0; nn < 4; ++nn) {
        const long idx = (long)(rowb + mm * 16) * ldc + colb + nn * 16;
        *(f32x4*)((float*)Cv + idx) = acc[mm][nn];
      }
    }
  } else {
    u16* C16 = (u16*)Cv;
    float* C32 = (float*)Cv;
    const int rowb = row0 + wm * 128, colb = col0 + wn * 64;
    bool vpath = false;
    if constexpr (VT) vpath = (col0 >= 2048);
    if (vpath) {
#pragma unroll
      for (int mm = 0; mm < 8; ++mm) {
#pragma unroll
        for (int nn = 0; nn < 4; ++nn) {
          const int col = colb + nn * 16 + lrow;
          const float bv = bias[col];
          const int dv = col - 2048;
          const int row = rowb + mm * 16 + lsel * 4;
          ushort4 o4;
          o4.x = f2b(acc[mm][nn][0] + bv);
          o4.y = f2b(acc[mm][nn][1] + bv);
          o4.z = f2b(acc[mm][nn][2] + bv);
          o4.w = f2b(acc[mm][nn][3] + bv);
          const long vaddr = ((long)((row >> 11) * 1024 + dv)) * 2048 + (row & 2047);
          *(ushort4*)&vtb[vaddr] = o4;
        }
      }
    } else {
#pragma unroll
      for (int mm = 0; mm < 8; ++mm) {
#pragma unroll
        for (int nn = 0; nn < 4; ++nn) {
          const int col = colb + nn * 16 + lrow;
          float bv = 0.f;
          if constexpr (EPI == 2 || EPI == 3) bv = bias[col];
#pragma unroll
          for (int r = 0; r < 4; ++r) {
            const int row = rowb + mm * 16 + lsel * 4 + r;
            const long idx = (long)row * ldc + col;
            const float v = acc[mm][nn][r] + bv;
            if constexpr (EPI == 0) C32[idx] = v;
            else if constexpr (EPI == 2) C16[idx] = f2b(v);
            else C16[idx] = f2b(gelu_tanh(v));
          }
        }
      }
    }
  }
}

// --------------------------------------------------------------- 128xBN GEMM
// proj/fc2: EPI=1 -> bf16 residual read + bf16 write (x = resid + Wx + b)
template <int BM, int BN, int WGM, int WGN, int EPI>
__global__ __launch_bounds__(WGM * WGN * 64)
void gemm_bt(const u16* __restrict__ A, const u16* __restrict__ Bt,
             void* Cv, const float* __restrict__ bias, const u16* resid,
             int M, int N, int K, int lda, int ldb, int ldc) {
  constexpr int BK = 64;
  constexpr int NT = WGM * WGN * 64;
  constexpr int WM = BM / WGM, WN = BN / WGN;
  constexpr int MF = WM / 16, NF = WN / 16;
  constexpr int AIT = (BM * BK) / (NT * 8);
  constexpr int BIT = (BN * BK) / (NT * 8);
  static_assert(AIT >= 1 && BIT >= 1, "staging shape");

  __shared__ u16 As[BM * BK];
  __shared__ u16 Bs[BN * BK];

  const int tid = threadIdx.x;
  const int wave = tid >> 6, lane = tid & 63;
  const int wr = wave / WGN, wc = wave % WGN;
  const int lrow = lane & 15, lsel = lane >> 4;
  const int row0 = blockIdx.y * BM;
  const int col0 = blockIdx.x * BN;

  f32x4 acc[MF][NF];
#pragma unroll
  for (int m = 0; m < MF; ++m)
#pragma unroll
    for (int n = 0; n < NF; ++n) acc[m][n] = f32x4{0.f, 0.f, 0.f, 0.f};

  for (int k0 = 0; k0 < K; k0 += BK) {
#pragma unroll
    for (int i = 0; i < AIT; ++i) {
      const int e = (i * NT + tid) * 8;
      const int rr = e >> 6, cc = e & 63;
      async16(A + (long)(row0 + rr) * lda + k0 + cc, &As[(i * NT + wave * 64) * 8]);
    }
#pragma unroll
    for (int i = 0; i < BIT; ++i) {
      const int e = (i * NT + tid) * 8;
      const int rr = e >> 6, cc = e & 63;
      async16(Bt + (long)(col0 + rr) * ldb + k0 + cc, &Bs[(i * NT + wave * 64) * 8]);
    }
    __syncthreads();
#pragma unroll
    for (int ks = 0; ks < 2; ++ks) {
      short8 af[MF], bfr[NF];
#pragma unroll
      for (int m = 0; m < MF; ++m)
        af[m] = *(const short8*)&As[(wr * WM + m * 16 + lrow) * BK + ks * 32 + lsel * 8];
#pragma unroll
      for (int n = 0; n < NF; ++n)
        bfr[n] = *(const short8*)&Bs[(wc * WN + n * 16 + lrow) * BK + ks * 32 + lsel * 8];
#pragma unroll
      for (int m = 0; m < MF; ++m)
#pragma unroll
        for (int n = 0; n < NF; ++n)
          acc[m][n] = __builtin_amdgcn_mfma_f32_16x16x32_bf16(af[m], bfr[n], acc[m][n], 0, 0, 0);
    }
    __syncthreads();
  }

#pragma unroll
  for (int m = 0; m < MF; ++m) {
#pragma unroll
    for (int n = 0; n < NF; ++n) {
      const int row = row0 + wr * WM + m * 16 + lsel * 4;
      const int col = col0 + wc * WN + n * 16 + lrow;
      float bv = 0.f;
      if constexpr (EPI == 1 || EPI == 2 || EPI == 3) bv = bias[col];
#pragma unroll
      for (int r = 0; r < 4; ++r) {
        const long idx = (long)(row + r) * ldc + col;
        const float v = acc[m][n][r] + bv;
        if constexpr (EPI == 0) ((float*)Cv)[idx] = v;
        else if constexpr (EPI == 1) ((u16*)Cv)[idx] = f2b(b2f(resid[idx]) + v);
        else if constexpr (EPI == 2) ((u16*)Cv)[idx] = f2b(v);
        else if constexpr (EPI == 3) ((u16*)Cv)[idx] = f2b(gelu_tanh(v));
        else ((u16*)Cv)[idx] = f2b(v);
      }
    }
  }
}

// ------------------------------------------------------------------ driver

extern "C" void kernel_launch(void* const* d_in, const int* in_sizes, int n_in,
                              void* d_out, int out_size, void* d_ws, size_t ws_size,
                              hipStream_t stream) {
  (void)in_sizes; (void)n_in; (void)out_size; (void)ws_size;
  const int*   ids    = (const int*)d_in[0];
  const float* wte    = (const float*)d_in[2];
  const float* wpe    = (const float*)d_in[3];
  const float* ln1_g  = (const float*)d_in[4];
  const float* ln1_b  = (const float*)d_in[5];
  const float* qkv_w  = (const float*)d_in[6];
  const float* qkv_b  = (const float*)d_in[7];
  const float* proj_w = (const float*)d_in[8];
  const float* proj_b = (const float*)d_in[9];
  const float* ln2_g  = (const float*)d_in[10];
  const float* ln2_b  = (const float*)d_in[11];
  const float* fc_w   = (const float*)d_in[12];
  const float* fc_b   = (const float*)d_in[13];
  const float* fc2_w  = (const float*)d_in[14];
  const float* fc2_b  = (const float*)d_in[15];
  const float* lnf_g  = (const float*)d_in[16];
  const float* lnf_b  = (const float*)d_in[17];
  float* out = (float*)d_out;

  char* base = (char*)d_ws;
  size_t off = 0;
  auto alloc = [&](size_t bytes) -> void* {
    void* r = base + off;
    off += (bytes + 255) & ~(size_t)255;
    return r;
  };
  u16*   wqkvT  = (u16*)alloc((size_t)4 * 3072 * 1024 * 2);
  u16*   wprojT = (u16*)alloc((size_t)4 * 1024 * 1024 * 2);
  u16*   wfcT   = (u16*)alloc((size_t)4 * 4096 * 1024 * 2);
  u16*   wfc2T  = (u16*)alloc((size_t)4 * 1024 * 4096 * 2);
  u16*   wteB   = (u16*)alloc((size_t)32000 * 1024 * 2);
  u16*   xbuf   = (u16*)alloc((size_t)4096 * 1024 * 2);
  u16*   hbf    = (u16*)alloc((size_t)4096 * 1024 * 2);
  u16*   qkvbf  = (u16*)alloc((size_t)4096 * 3072 * 2);
  u16*   vTb    = (u16*)alloc((size_t)32 * 64 * 2048 * 2);
  u16*   obf    = (u16*)alloc((size_t)4096 * 1024 * 2);
  u16*   fcbf   = (u16*)alloc((size_t)4096 * 4096 * 2);

  // ---- prep: weight casts/transposes + fused embed+LN1(l=0)
  castbf_k<<<32000, 256, 0, stream>>>(wte, wteB, (long)32000 * 1024 / 4);
  tcast32_k<<<dim3(96, 32, 4), 256, 0, stream>>>(qkv_w, wqkvT, 1024, 3072,
                                                 (long)1024 * 3072, (long)1024 * 3072);
  tcast32_k<<<dim3(32, 32, 4), 256, 0, stream>>>(proj_w, wprojT, 1024, 1024,
                                                 (long)1024 * 1024, (long)1024 * 1024);
  tcast32_k<<<dim3(128, 32, 4), 256, 0, stream>>>(fc_w, wfcT, 1024, 4096,
                                                  (long)1024 * 4096, (long)1024 * 4096);
  tcast32_k<<<dim3(32, 128, 4), 256, 0, stream>>>(fc2_w, wfc2T, 4096, 1024,
                                                  (long)4096 * 1024, (long)4096 * 1024);
  embed_ln_k<<<4096, 256, 0, stream>>>(ids, wte, wpe, ln1_g, ln1_b, xbuf, hbf);

  for (int l = 0; l < 4; ++l) {
    if (l > 0)
      ln_bf16_k<<<4096, 256, 0, stream>>>(xbuf, ln1_g + l * 1024, ln1_b + l * 1024, hbf);
    // qkv = LN1 @ Wqkv + b; Q,K -> qkvbf; V -> vTb (transposed in-epilogue)
    gemm8<2, false, true><<<dim3(12, 16), 512, 0, stream>>>(
        hbf, wqkvT + (size_t)l * 3072 * 1024, qkvbf, qkv_b + l * 3072,
        1024, 1024, 1024, 3072, vTb);
    // flash attention: bh-major grid -> per-head K/V stays in one XCD's L2
    flash_k<<<dim3(32, 16), 256, 0, stream>>>(qkvbf, vTb, obf);
    // x = x + O @ Wproj + b   (bf16 residual stream)
    gemm_bt<128, 64, 2, 2, 1><<<dim3(16, 32, 1), 256, 0, stream>>>(
        obf, wprojT + (size_t)l * 1024 * 1024, xbuf, proj_b + l * 1024, xbuf,
        4096, 1024, 1024, 1024, 1024, 1024);
    ln_bf16_k<<<4096, 256, 0, stream>>>(xbuf, ln2_g + l * 1024, ln2_b + l * 1024, hbf);
    // fcact = gelu(LN2 @ Wfc + b) -> bf16   (8-phase 256^2, scalar epi)
    gemm8<3, false, false><<<dim3(16, 16), 512, 0, stream>>>(
        hbf, wfcT + (size_t)l * 4096 * 1024, fcbf, fc_b + l * 4096,
        1024, 1024, 1024, 4096, nullptr);
    // x = x + fcact @ Wfc2 + b   (bf16 residual stream)
    gemm_bt<128, 64, 2, 2, 1><<<dim3(16, 32, 1), 256, 0, stream>>>(
        fcbf, wfc2T + (size_t)l * 1024 * 4096, xbuf, fc2_b + l * 1024, xbuf,
        4096, 1024, 4096, 4096, 4096, 1024);
  }
  ln_bf16_k<<<4096, 256, 0, stream>>>(xbuf, lnf_g, lnf_b, hbf);
  // logits = lnf @ wte^T  (8-phase 256^2, swapped + full-line f32x4 stores)
  gemm8<0, true, false><<<dim3(125, 16), 512, 0, stream>>>(
      hbf, wteB, out, nullptr, 1024, 1024, 1024, 32000, nullptr);
}